// Round 1
// baseline (1430.004 us; speedup 1.0000x reference)
//
#include <hip/hip_runtime.h>
#include <hip/hip_bf16.h>
#include <math.h>

#define N_TOK 1048576
#define BSEG  4096
#define DIM   256
#define HID   128

typedef __attribute__((ext_vector_type(8))) short short8;
typedef __attribute__((ext_vector_type(4))) short short4v;
typedef __attribute__((ext_vector_type(4))) float f32x4;

__device__ __forceinline__ short f2bf(float f) {
    union { float f; unsigned u; } v; v.f = f;
    unsigned r = v.u + 0x7fff + ((v.u >> 16) & 1);   // RNE
    return (short)(r >> 16);
}
__device__ __forceinline__ float bf2f(short s) {
    union { unsigned u; float f; } v;
    v.u = ((unsigned)(unsigned short)s) << 16;
    return v.f;
}

// ---- prep: W1 [D][H] fp32 -> W1T [H][D] bf16 (k-contiguous rows) ----
__global__ void prep_w1t(const float* __restrict__ W1, short* __restrict__ W1T) {
    int i = blockIdx.x * blockDim.x + threadIdx.x;   // 0..32767
    int h = i >> 8;        // row of W1T
    int k = i & 255;       // col of W1T (= row of W1)
    W1T[i] = f2bf(W1[k * HID + h]);
}

// ---- fused main: logits (MFMA) -> z=exp(s) -> unnormalized pooling ----
__launch_bounds__(256, 3)
__global__ void main_kernel(const float* __restrict__ x,
                            const int*  __restrict__ seg,
                            const short* __restrict__ W1T,
                            const float* __restrict__ b1,
                            const float* __restrict__ W2,
                            const float* __restrict__ b2,
                            float* __restrict__ ctx,     // d_out[0 .. B*D)
                            float* __restrict__ zout,    // d_out + B*D
                            float* __restrict__ denom) {
    // LDS: 64 tokens x 256 k bf16, row stride 264 shorts (528 B, 16B-aligned, pad kills conflicts)
    __shared__ __align__(16) short x_lds[64 * 264];      // 33792 B
    __shared__ float s_part[4][64];
    __shared__ float z_lds[64];
    __shared__ int   seg_lds[64];

    const int tid  = threadIdx.x;
    const int wv   = tid >> 6;        // wave 0..3
    const int lane = tid & 63;
    const int q    = lane >> 4;       // quad 0..3
    const int c    = lane & 15;       // col 0..15
    const long base_tok = (long)blockIdx.x * 64;

    if (tid < 64) seg_lds[tid] = seg[base_tok + tid];

    // stage x chunk -> LDS bf16, coalesced float4 loads (one wave per token row)
    const float4* xg = reinterpret_cast<const float4*>(x) + base_tok * 64;
#pragma unroll
    for (int it = 0; it < 16; ++it) {
        int flat  = it * 256 + tid;
        int token = flat >> 6, kq = flat & 63;
        float4 v = xg[flat];
        short4v p = { f2bf(v.x), f2bf(v.y), f2bf(v.z), f2bf(v.w) };
        *reinterpret_cast<short4v*>(&x_lds[token * 264 + kq * 4]) = p;
    }

    // preload this wave's W1T B-fragments (hidden tiles wv and wv+4), 64 VGPRs
    short8 bf[2][8];
#pragma unroll
    for (int ti = 0; ti < 2; ++ti) {
        int t = wv + 4 * ti;
#pragma unroll
        for (int kk = 0; kk < 8; ++kk) {
            bf[ti][kk] = *reinterpret_cast<const short8*>(
                W1T + (t * 16 + c) * 256 + kk * 32 + q * 8);
        }
    }
    const float b1v0 = b1[wv * 16 + c];
    const float b1v1 = b1[(wv + 4) * 16 + c];
    const float w2v0 = W2[wv * 16 + c];
    const float w2v1 = W2[(wv + 4) * 16 + c];
    const float b2s  = b2[0];

    __syncthreads();

    // 4 token-tiles of 16; each wave does all tokens x its 32 hidden
#pragma unroll
    for (int tt = 0; tt < 4; ++tt) {
        f32x4 acc0 = {0.f, 0.f, 0.f, 0.f};
        f32x4 acc1 = {0.f, 0.f, 0.f, 0.f};
        const short* arow = &x_lds[(tt * 16 + c) * 264 + q * 8];
#pragma unroll
        for (int kk = 0; kk < 8; ++kk) {
            short8 a = *reinterpret_cast<const short8*>(arow + kk * 32);
            acc0 = __builtin_amdgcn_mfma_f32_16x16x32_bf16(a, bf[0][kk], acc0, 0, 0, 0);
            acc1 = __builtin_amdgcn_mfma_f32_16x16x32_bf16(a, bf[1][kk], acc1, 0, 0, 0);
        }
        // tanh + W2 partial dot (this wave's 32 hidden), then reduce over 16 cols
        float part[4];
#pragma unroll
        for (int r = 0; r < 4; ++r) {
            float h0 = tanhf(acc0[r] + b1v0);
            float h1 = tanhf(acc1[r] + b1v1);
            part[r] = h0 * w2v0 + h1 * w2v1;
        }
#pragma unroll
        for (int r = 0; r < 4; ++r) {
            float v = part[r];
            v += __shfl_xor(v, 1);
            v += __shfl_xor(v, 2);
            v += __shfl_xor(v, 4);
            v += __shfl_xor(v, 8);
            part[r] = v;
        }
        if (c == 0) {
            float4 st = make_float4(part[0], part[1], part[2], part[3]);
            *reinterpret_cast<float4*>(&s_part[wv][tt * 16 + q * 4]) = st;
        }
    }
    __syncthreads();

    // combine wave partials -> s -> z = exp(s)  (deferred-normalization softmax)
    if (tid < 64) {
        float s = s_part[0][tid] + s_part[1][tid] + s_part[2][tid] + s_part[3][tid] + b2s;
        float z = __expf(s) * 0.f + expf(s);  // accurate expf
        z_lds[tid] = z;
        zout[base_tok + tid] = z;             // normalized later
    }
    __syncthreads();

    // pooling: thread j owns feature d=j; walk tokens, flush on segment boundary
    {
        const int j = tid;
        float acc = 0.f;
        int prev = seg_lds[0];
#pragma unroll 4
        for (int n = 0; n < 64; ++n) {
            int sg = seg_lds[n];
            if (sg != prev) {
                atomicAdd(&ctx[(long)prev * DIM + j], acc);
                acc = 0.f;
                prev = sg;
            }
            acc += z_lds[n] * bf2f(x_lds[n * 264 + j]);
        }
        atomicAdd(&ctx[(long)prev * DIM + j], acc);
    }
    if (tid == 0) {
        float az = 0.f;
        int pv = seg_lds[0];
        for (int n = 0; n < 64; ++n) {
            int sg = seg_lds[n];
            if (sg != pv) { atomicAdd(&denom[pv], az); az = 0.f; pv = sg; }
            az += z_lds[n];
        }
        atomicAdd(&denom[pv], az);
    }
}

// ---- finalize: normalize context rows and attention weights in place ----
__global__ void finalize(float* __restrict__ out, const float* __restrict__ denom,
                         const int* __restrict__ seg) {
    long idx = (long)blockIdx.x * 256 + threadIdx.x;
    const long BD = (long)BSEG * DIM;
    if (idx < BD) {
        float dn = denom[idx >> 8];
        float v = out[idx];
        out[idx] = dn > 0.f ? v / dn : 0.f;
    } else {
        long n = idx - BD;
        float dn = denom[seg[n]];
        float z = out[idx];
        out[idx] = dn > 0.f ? z / dn : 0.f;
    }
}

extern "C" void kernel_launch(void* const* d_in, const int* in_sizes, int n_in,
                              void* d_out, int out_size, void* d_ws, size_t ws_size,
                              hipStream_t stream) {
    const float* x  = (const float*)d_in[0];
    const int*   sg = (const int*)d_in[1];
    const float* W1 = (const float*)d_in[2];
    const float* b1 = (const float*)d_in[3];
    const float* W2 = (const float*)d_in[4];
    const float* b2 = (const float*)d_in[5];
    float* out = (float*)d_out;

    short* W1T   = (short*)d_ws;                       // 64 KiB
    float* denom = (float*)((char*)d_ws + 65536);      // 16 KiB
    const long BD = (long)BSEG * DIM;

    hipMemsetAsync(out, 0, BD * sizeof(float), stream);        // ctx accumulators
    hipMemsetAsync(denom, 0, BSEG * sizeof(float), stream);

    prep_w1t<<<(HID * DIM) / 256, 256, 0, stream>>>(W1, W1T);
    main_kernel<<<N_TOK / 64, 256, 0, stream>>>(x, sg, W1T, b1, W2, b2,
                                                out, out + BD, denom);
    finalize<<<(int)((BD + N_TOK) / 256), 256, 0, stream>>>(out, denom, sg);
}